// Round 3
// baseline (289.508 us; speedup 1.0000x reference)
//
#include <hip/hip_runtime.h>
#include <hip/hip_bf16.h>
#include <math.h>

#define GG 8192      // graphs = B*T
#define NODESN 23
#define KK 8
#define DIN 16
#define HH 128
#define RHH 128
#define EPG (NODESN*KK)   // 184 edges per graph
#define TTT 128
#define BBB 64

// ---------------------------------------------------------------------------
// DPP cross-lane add (VALU pipe -- NOT the DS pipe, unlike __shfl_xor).
// ---------------------------------------------------------------------------
template<int CTRL>
static __device__ __forceinline__ float dpp_add(float v) {
    int x = __builtin_amdgcn_update_dpp(0, __float_as_int(v), CTRL, 0xF, 0xF, true);
    return v + __int_as_float(x);
}
#define DPP_XOR1 0xB1   // quad_perm [1,0,3,2]
#define DPP_XOR2 0x4E   // quad_perm [2,3,0,1]
#define DPP_MIR7 0x141  // row_half_mirror: lane l <-> l^7 within 8-lane half-row
#define DPP_SHL4 0x104  // row_shl:4 (lane l <- lane l+4)

// ---------------------------------------------------------------------------
// Kernel 1 (fused): per-graph GCN layer-1 + aggregation + layer-2 row.
// 4 graphs per block, 256 threads, 2048 blocks, ~56 KB LDS -> 2 blocks/CU.
//
// R10 rationale: old gcn_hsum was DS-pipe-bound (per wave ~48 broadcast
// ds_read_b128 for xs in the t1 phase + ~45 scalar gathers in agg, ~8
// blocks/CU deep).  Fixes:
//  (a) x rows are block-uniform -> read via uniform loads (backend
//      scalarizes to s_load; operands come from SGPRs) -> the xs LDS
//      array and ALL t1-phase DS reads are gone.
//  (b) W1 column j lives in VGPRs, loaded once per block, reused 4x.
//  (c) layer-2 (old seq_kernel) computed in-block from LDS hsum ->
//      hsum never round-trips HBM, one kernel launch removed.
// ---------------------------------------------------------------------------
__global__ __launch_bounds__(256) void gcn_fused(
    const float* __restrict__ x, const int* __restrict__ esrc,
    const int* __restrict__ runner,
    const float* __restrict__ W1, const float* __restrict__ b1,
    const float* __restrict__ W2, const float* __restrict__ b2,
    float* __restrict__ seq)
{
    __shared__ float t1[4 * NODESN * HH];   // 47104 B
    __shared__ int   srcs[4 * EPG];         //  2944 B
    __shared__ float red4[4 * 256];         //  4096 B
    __shared__ float hs[4 * HH];            //  2048 B

    const int g0   = blockIdx.x * 4;
    const int tid  = threadIdx.x;
    const int j    = tid & 127;
    const int half = tid >> 7;

    // ---- stage edge lists (local indices) for 4 graphs
    for (int i = tid; i < 4 * EPG; i += 256) {
        int gg = i / EPG;
        srcs[i] = esrc[(size_t)g0 * EPG + i] - (g0 + gg) * NODESN;
    }

    // ---- W1 column j -> registers (once per block, reused for 4 graphs)
    float w[DIN];
    #pragma unroll
    for (int k = 0; k < DIN; k++) w[k] = W1[k * HH + j];
    const float b1j = b1[j];

    // ---- phase 1: t1 = x @ W1 (pre-bias). x rows are uniform -> s_load.
    const int n0 = half ? 12 : 0;
    const int n1 = half ? NODESN : 12;
    for (int gg = 0; gg < 4; gg++) {
        const float* xgp = x + (size_t)(g0 + gg) * NODESN * DIN;
        for (int n = n0; n < n1; n++) {
            const float4* xr = (const float4*)(xgp + n * DIN);
            float4 a0 = xr[0], a1 = xr[1], a2 = xr[2], a3 = xr[3];
            float acc;
            acc = fmaf(a0.x, w[0],  fmaf(a0.y, w[1],  fmaf(a0.z, w[2],  fmaf(a0.w, w[3],
                  fmaf(a1.x, w[4],  fmaf(a1.y, w[5],  fmaf(a1.z, w[6],  fmaf(a1.w, w[7],
                  fmaf(a2.x, w[8],  fmaf(a2.y, w[9],  fmaf(a2.z, w[10], fmaf(a2.w, w[11],
                  fmaf(a3.x, w[12], fmaf(a3.y, w[13], fmaf(a3.z, w[14], fmaf(a3.w, w[15],
                  0.f))))))))))))))));
            t1[((gg * NODESN + n) << 7) + j] = acc;
        }
    }
    __syncthreads();

    // ---- phase 2: runner-neighborhood aggregation (per graph)
    for (int gg = 0; gg < 4; gg++) {
        const int r = runner[g0 + gg];
        const int* sg = srcs + gg * EPG;
        const float* tg = t1 + ((gg * NODESN) << 7);
        float part = 0.f;
        for (int slot = half; slot < 9; slot += 2) {
            int node = (slot < 8) ? sg[r * KK + slot] : r;
            float acc = tg[(node << 7) + j];
            #pragma unroll
            for (int k = 0; k < KK; k++) acc += tg[(sg[node * KK + k] << 7) + j];
            part += fmaxf(acc * (1.f / 9.f) + b1j, 0.f);
        }
        red4[gg * 256 + tid] = part;
    }
    __syncthreads();

    // ---- combine the two half-partials: hs[gg][j]
    {
        int gg = tid >> 7, jj = tid & 127;
        hs[gg * HH + jj]       = red4[gg * 256 + jj]       + red4[gg * 256 + jj + 128];
        hs[(gg + 2) * HH + jj] = red4[(gg + 2) * 256 + jj] + red4[(gg + 2) * 256 + jj + 128];
    }
    __syncthreads();

    // ---- phase 3: seq row = relu((1/9) * hs @ W2 + b2), two rows per thread
    {
        const float b2j = b2[j];
        const float* h0 = hs + (half * 2) * HH;
        float acc0 = 0.f, acc1 = 0.f;
        for (int k = 0; k < HH; k += 4) {
            float w0  = W2[(k + 0) * HH + j];
            float w1  = W2[(k + 1) * HH + j];
            float w2v = W2[(k + 2) * HH + j];
            float w3  = W2[(k + 3) * HH + j];
            float4 hv0 = *(const float4*)(h0 + k);
            float4 hv1 = *(const float4*)(h0 + HH + k);
            acc0 = fmaf(hv0.x, w0, fmaf(hv0.y, w1, fmaf(hv0.z, w2v, fmaf(hv0.w, w3, acc0))));
            acc1 = fmaf(hv1.x, w0, fmaf(hv1.y, w1, fmaf(hv1.z, w2v, fmaf(hv1.w, w3, acc1))));
        }
        seq[(size_t)(g0 + half * 2 + 0) * HH + j] = fmaxf(acc0 * (1.f / 9.f) + b2j, 0.f);
        seq[(size_t)(g0 + half * 2 + 1) * HH + j] = fmaxf(acc1 * (1.f / 9.f) + b2j, 0.f);
    }
}

// ---------------------------------------------------------------------------
// Kernel 3: transpose W_ih [384,128] -> WT [128,384]
// ---------------------------------------------------------------------------
__global__ void transpose_wih(const float* __restrict__ W, float* __restrict__ WT)
{
    int idx = blockIdx.x * 256 + threadIdx.x;
    if (idx < 3 * RHH * RHH) {
        int jj = idx / RHH, kk = idx - jj * RHH;
        WT[kk * (3 * RHH) + jj] = W[idx];
    }
}

// ---------------------------------------------------------------------------
// Kernel 4: xg = seq @ W_ih^T + b_ih   [8192,128]@[128,384]
// ---------------------------------------------------------------------------
__global__ __launch_bounds__(384) void xg_kernel(
    const float* __restrict__ seq, const float* __restrict__ WT,
    const float* __restrict__ b_ih, float* __restrict__ xg)
{
    const int tid = threadIdx.x;
    const int m0 = blockIdx.x * 8;
    const float* srow = seq + (size_t)m0 * RHH;
    float acc[8];
    const float bv = b_ih[tid];
    #pragma unroll
    for (int mi = 0; mi < 8; mi++) acc[mi] = bv;
    for (int k = 0; k < RHH; k += 4) {
        float w0 = WT[(k+0)*384 + tid];
        float w1 = WT[(k+1)*384 + tid];
        float w2 = WT[(k+2)*384 + tid];
        float w3 = WT[(k+3)*384 + tid];
        #pragma unroll
        for (int mi = 0; mi < 8; mi++) {
            float4 sv = *(const float4*)(srow + mi * RHH + k);
            acc[mi] = fmaf(sv.x, w0, fmaf(sv.y, w1, fmaf(sv.z, w2, fmaf(sv.w, w3, acc[mi]))));
        }
    }
    #pragma unroll
    for (int mi = 0; mi < 8; mi++)
        xg[(size_t)(m0 + mi) * 384 + tid] = acc[mi];
}

// ---------------------------------------------------------------------------
// Kernel 5: GRU (unchanged from R9 -- serves as the A/B control this round).
// ---------------------------------------------------------------------------
#define CHUNK 32
#define XGB_FLOATS (CHUNK * HH * 4)      // 16384 floats = 64 KB

__global__ __launch_bounds__(512)
__attribute__((amdgpu_waves_per_eu(2, 2)))
void gru_kernel(
    const float* __restrict__ xg, const float* __restrict__ W_hh,
    const float* __restrict__ b_hh, const float* __restrict__ Wp,
    const float* __restrict__ bp, float* __restrict__ out)
{
    __shared__ float xgbuf[XGB_FLOATS];          // [tl][i][{xr,xz,xn,pad}]
    __shared__ float houtb[(CHUNK + 2) * HH];    // rows 1..32 = h(t); row 32 also carry
    __shared__ float wps[2 * RHH + 2];           // Wp + bp

    const int b   = blockIdx.x;
    const int tid = threadIdx.x;
    const int kq  = tid & 7;       // k-eighth, lane bits 0-2 (DPP butterfly domain)
    const int i0  = tid >> 3;      // unit pair 0..63
    const int uhf = kq >> 2;       // which unit of the pair this lane's gates handle
    const int u   = 2 * i0 + uhf;  // this lane's gate unit

    // ---- preload W_hh slices: rows {2i0, 2i0+1} x {r,z,n}, cols [16kq,16kq+16),
    // phase-rotated p=(m+kq)&3 (matches the h-read rotation below).
    float4 wr0[4], wz0[4], wn0[4], wr1[4], wz1[4], wn1[4];
    int hof[4];
    {
        const float* w0 = W_hh + (size_t)(2 * i0) * RHH + kq * 16;
        #pragma unroll
        for (int m = 0; m < 4; m++) {
            const int off = 4 * ((m + kq) & 3);
            hof[m] = kq * 16 + off;
            wr0[m] = *(const float4*)(w0 + off);
            wz0[m] = *(const float4*)(w0 + RHH * RHH + off);
            wn0[m] = *(const float4*)(w0 + 2 * RHH * RHH + off);
            wr1[m] = *(const float4*)(w0 + RHH + off);
            wz1[m] = *(const float4*)(w0 + RHH * RHH + RHH + off);
            wn1[m] = *(const float4*)(w0 + 2 * RHH * RHH + RHH + off);
        }
    }
    const float bhr = b_hh[u];
    const float bhz = b_hh[RHH + u];
    const float bhn = b_hh[2 * RHH + u];

    if (tid < 2 * RHH) wps[tid] = Wp[tid];
    if (tid < 2)       wps[2 * RHH + tid] = bp[tid];
    if (tid < HH)      houtb[CHUNK * HH + tid] = 0.f;   // carry row = h(-1) = 0
    float hprev = 0.f;

    const float* xbase = xg + (size_t)b * TTT * 3 * RHH;
    float* outb = out + (size_t)b * TTT * 2;

    for (int c = 0; c < TTT / CHUNK; c++) {
        // ---- refill xgbuf for chunk c, repacking to [tl][i][{r,z,n,pad}]
        #pragma unroll
        for (int k2 = 0; k2 < 8; k2++) {
            int slot = tid + (k2 << 9);          // 0..4095
            int tl = slot >> 7, ii = slot & 127;
            const float* gsrc = xbase + (size_t)(c * CHUNK + tl) * 384 + ii;
            float4 v;
            v.x = gsrc[0]; v.y = gsrc[128]; v.z = gsrc[256]; v.w = 0.f;
            *(float4*)&xgbuf[slot << 2] = v;
        }
        // ---- project previous chunk: out = houtb[1..32] @ Wp + bp
        if (c > 0) {
            const int s  = tid & 7;              // 16-float k-slice
            const int cc = (tid >> 3) & 1;
            const int tl = tid >> 4;             // 0..31
            const float* hr = &houtb[(tl + 1) * HH + s * 16];
            float acc = 0.f;
            #pragma unroll
            for (int m = 0; m < 16; m += 4) {
                float4 hv = *(const float4*)(hr + m);
                int k = s * 16 + m;
                acc = fmaf(hv.x, wps[(k+0)*2 + cc],
                      fmaf(hv.y, wps[(k+1)*2 + cc],
                      fmaf(hv.z, wps[(k+2)*2 + cc],
                      fmaf(hv.w, wps[(k+3)*2 + cc], acc))));
            }
            acc = dpp_add<DPP_XOR1>(acc);
            acc = dpp_add<DPP_XOR2>(acc);
            acc = dpp_add<DPP_SHL4>(acc);        // valid in lanes s<4
            if (s == 0)
                outb[((c - 1) * CHUNK + tl) * 2 + cc] = acc + wps[2 * RHH + cc];
        }
        __syncthreads();

        // ---- 32 steps; per step per thread: 4 ds_read_b128 (h) + 1 (xg,
        // pipelined from previous iteration) + 1 masked write
        float4 xgv = *(const float4*)&xgbuf[u << 2];   // tl=0 row
        for (int tl = 0; tl < CHUNK; tl++) {
            const float* hrow = &houtb[(tl == 0 ? CHUNK : tl) * HH];
            // prefetch next step's xg row (xgbuf is stable within the chunk)
            float4 xgn = xgv;
            if (tl + 1 < CHUNK)
                xgn = *(const float4*)&xgbuf[((tl + 1) * HH + u) << 2];

            float ar0 = 0.f, az0 = 0.f, an0 = 0.f;
            float ar1 = 0.f, az1 = 0.f, an1 = 0.f;
            #pragma unroll
            for (int m = 0; m < 4; m++) {
                float4 hv = *(const float4*)(hrow + hof[m]);
                ar0 = fmaf(hv.x, wr0[m].x, fmaf(hv.y, wr0[m].y, fmaf(hv.z, wr0[m].z, fmaf(hv.w, wr0[m].w, ar0))));
                az0 = fmaf(hv.x, wz0[m].x, fmaf(hv.y, wz0[m].y, fmaf(hv.z, wz0[m].z, fmaf(hv.w, wz0[m].w, az0))));
                an0 = fmaf(hv.x, wn0[m].x, fmaf(hv.y, wn0[m].y, fmaf(hv.z, wn0[m].z, fmaf(hv.w, wn0[m].w, an0))));
                ar1 = fmaf(hv.x, wr1[m].x, fmaf(hv.y, wr1[m].y, fmaf(hv.z, wr1[m].z, fmaf(hv.w, wr1[m].w, ar1))));
                az1 = fmaf(hv.x, wz1[m].x, fmaf(hv.y, wz1[m].y, fmaf(hv.z, wz1[m].z, fmaf(hv.w, wz1[m].w, az1))));
                an1 = fmaf(hv.x, wn1[m].x, fmaf(hv.y, wn1[m].y, fmaf(hv.z, wn1[m].z, fmaf(hv.w, wn1[m].w, an1))));
            }
            // 8-lane butterfly: xor1, xor2 (quad sums), half-mirror (l^7)
            ar0 = dpp_add<DPP_XOR1>(ar0); ar0 = dpp_add<DPP_XOR2>(ar0); ar0 = dpp_add<DPP_MIR7>(ar0);
            az0 = dpp_add<DPP_XOR1>(az0); az0 = dpp_add<DPP_XOR2>(az0); az0 = dpp_add<DPP_MIR7>(az0);
            an0 = dpp_add<DPP_XOR1>(an0); an0 = dpp_add<DPP_XOR2>(an0); an0 = dpp_add<DPP_MIR7>(an0);
            ar1 = dpp_add<DPP_XOR1>(ar1); ar1 = dpp_add<DPP_XOR2>(ar1); ar1 = dpp_add<DPP_MIR7>(ar1);
            az1 = dpp_add<DPP_XOR1>(az1); az1 = dpp_add<DPP_XOR2>(az1); az1 = dpp_add<DPP_MIR7>(az1);
            an1 = dpp_add<DPP_XOR1>(an1); an1 = dpp_add<DPP_XOR2>(an1); an1 = dpp_add<DPP_MIR7>(an1);

            // lane-specialized gates: lower half-group -> unit 2i0, upper -> 2i0+1
            float ar = uhf ? ar1 : ar0;
            float az = uhf ? az1 : az0;
            float an = uhf ? an1 : an0;

            float sr = xgv.x + ar + bhr;
            float sz = xgv.y + az + bhz;
            float rg = 1.f / (1.f + __expf(-sr));
            float zg = 1.f / (1.f + __expf(-sz));
            float tv = fmaf(rg, an + bhn, xgv.z);
            tv = fminf(fmaxf(tv, -15.f), 15.f);
            float e2 = __expf(-2.f * tv);
            float ng = (1.f - e2) / (1.f + e2);
            hprev = fmaf(zg, hprev, (1.f - zg) * ng);
            if ((kq & 3) == 0) houtb[(tl + 1) * HH + u] = hprev;  // kq=0 -> 2i0, kq=4 -> 2i0+1
            xgv = xgn;
            __syncthreads();
        }
    }

    // ---- project the last chunk
    {
        const int s  = tid & 7;
        const int cc = (tid >> 3) & 1;
        const int tl = tid >> 4;
        const float* hr = &houtb[(tl + 1) * HH + s * 16];
        float acc = 0.f;
        #pragma unroll
        for (int m = 0; m < 16; m += 4) {
            float4 hv = *(const float4*)(hr + m);
            int k = s * 16 + m;
            acc = fmaf(hv.x, wps[(k+0)*2 + cc],
                  fmaf(hv.y, wps[(k+1)*2 + cc],
                  fmaf(hv.z, wps[(k+2)*2 + cc],
                  fmaf(hv.w, wps[(k+3)*2 + cc], acc))));
        }
        acc = dpp_add<DPP_XOR1>(acc);
        acc = dpp_add<DPP_XOR2>(acc);
        acc = dpp_add<DPP_SHL4>(acc);
        if (s == 0)
            outb[((TTT / CHUNK - 1) * CHUNK + tl) * 2 + cc] = acc + wps[2 * RHH + cc];
    }
}

extern "C" void kernel_launch(void* const* d_in, const int* in_sizes, int n_in,
                              void* d_out, int out_size, void* d_ws, size_t ws_size,
                              hipStream_t stream)
{
    const float* x      = (const float*)d_in[0];
    const int*   eidx   = (const int*)d_in[1];
    const int*   runner = (const int*)d_in[2];
    const float* W1     = (const float*)d_in[3];
    const float* b1     = (const float*)d_in[4];
    const float* W2     = (const float*)d_in[5];
    const float* b2     = (const float*)d_in[6];
    const float* W_ih   = (const float*)d_in[7];
    const float* W_hh   = (const float*)d_in[8];
    const float* b_ih   = (const float*)d_in[9];
    const float* b_hh   = (const float*)d_in[10];
    const float* Wp     = (const float*)d_in[11];
    const float* bp     = (const float*)d_in[12];
    float* out = (float*)d_out;

    float* seq = (float*)d_ws;                       // 8192*128   [0, 4 MB)
    float* xg  = seq + (size_t)GG * HH;              // 8192*384   [4, 16.6 MB)
    float* WT  = xg + (size_t)GG * 3 * RHH;          // 128*384

    transpose_wih<<<192, 256, 0, stream>>>(W_ih, WT);
    gcn_fused<<<GG / 4, 256, 0, stream>>>(x, eidx, runner, W1, b1, W2, b2, seq);
    xg_kernel<<<GG / 8, 384, 0, stream>>>(seq, WT, b_ih, xg);
    gru_kernel<<<BBB, 512, 0, stream>>>(xg, W_hh, b_hh, Wp, bp, out);
}

// Round 5
// 266.924 us; speedup vs baseline: 1.0846x; 1.0846x over previous
//
#include <hip/hip_runtime.h>
#include <hip/hip_bf16.h>
#include <math.h>

#define GG 8192      // graphs = B*T
#define NODESN 23
#define KK 8
#define DIN 16
#define HH 128
#define RHH 128
#define EPG (NODESN*KK)   // 184 edges per graph
#define TTT 128
#define BBB 64

// ---------------------------------------------------------------------------
// DPP cross-lane add (VALU pipe -- NOT the DS pipe, unlike __shfl_xor).
// ---------------------------------------------------------------------------
template<int CTRL>
static __device__ __forceinline__ float dpp_add(float v) {
    int x = __builtin_amdgcn_update_dpp(0, __float_as_int(v), CTRL, 0xF, 0xF, true);
    return v + __int_as_float(x);
}
#define DPP_XOR1 0xB1   // quad_perm [1,0,3,2]
#define DPP_XOR2 0x4E   // quad_perm [2,3,0,1]
#define DPP_MIR7 0x141  // row_half_mirror: lane l <-> l^7 within 8-lane half-row
#define DPP_SHL4 0x104  // row_shl:4 (lane l <- lane l+4)

// ---------------------------------------------------------------------------
// Kernel 1: per-graph GCN up to hsum (R9 version, reverted from R10 fusion:
// 8192 small blocks -> ~32 waves/CU latency hiding, which the fused 2-block/CU
// variant lost; fusion cost +44 us).
// ---------------------------------------------------------------------------
__global__ __launch_bounds__(256) void gcn_hsum(
    const float* __restrict__ x, const int* __restrict__ esrc,
    const int* __restrict__ runner,
    const float* __restrict__ W1, const float* __restrict__ b1,
    float* __restrict__ hsum_g)
{
    __shared__ float xs[NODESN * DIN];
    __shared__ int   srcs[EPG];
    __shared__ float t1[NODESN * HH];
    __shared__ float red[256];

    const int g   = blockIdx.x;
    const int tid = threadIdx.x;
    const int j   = tid & 127;
    const int nh  = tid >> 7;

    for (int i = tid; i < NODESN * DIN; i += 256) xs[i] = x[g * NODESN * DIN + i];
    for (int i = tid; i < EPG; i += 256)          srcs[i] = esrc[g * EPG + i] - g * NODESN;

    float w[DIN];
    #pragma unroll
    for (int k = 0; k < DIN; k++) w[k] = W1[k * HH + j];
    const float b1j = b1[j];
    __syncthreads();

    const int n0 = nh * 12;
    const int n1 = nh ? NODESN : 12;
    for (int n = n0; n < n1; n++) {
        float acc = 0.f;
        #pragma unroll
        for (int k = 0; k < DIN; k += 4) {
            float4 xv = *(const float4*)&xs[n * DIN + k];
            acc = fmaf(xv.x, w[k], fmaf(xv.y, w[k+1], fmaf(xv.z, w[k+2], fmaf(xv.w, w[k+3], acc))));
        }
        t1[n * HH + j] = acc;
    }
    __syncthreads();

    const int r = runner[g];
    float part = 0.f;
    for (int slot = nh; slot < 9; slot += 2) {
        int node = (slot < 8) ? srcs[r * KK + slot] : r;
        float acc = t1[node * HH + j];
        #pragma unroll
        for (int k = 0; k < KK; k++) acc += t1[srcs[node * KK + k] * HH + j];
        part += fmaxf(acc * (1.f / 9.f) + b1j, 0.f);
    }
    red[tid] = part;
    __syncthreads();
    if (tid < HH) hsum_g[(size_t)g * HH + tid] = red[tid] + red[tid + 128];
}

// ---------------------------------------------------------------------------
// Kernel 2: seq = relu((1/9) * hsum @ W2 + b2), 16 graphs per block (R9).
// ---------------------------------------------------------------------------
__global__ __launch_bounds__(256) void seq_kernel(
    const float* __restrict__ hsum_g, const float* __restrict__ W2,
    const float* __restrict__ b2, float* __restrict__ seq)
{
    __shared__ float hs[16 * HH];
    const int tid = threadIdx.x;
    const int j = tid & 127, mh = tid >> 7;
    const size_t base = (size_t)blockIdx.x * 16 * HH;

    for (int v = tid; v < 16 * HH / 4; v += 256)
        ((float4*)hs)[v] = ((const float4*)(hsum_g + base))[v];
    __syncthreads();

    float acc[8];
    #pragma unroll
    for (int m = 0; m < 8; m++) acc[m] = 0.f;
    const float* hrow = hs + mh * 8 * HH;
    for (int k = 0; k < HH; k += 4) {
        float w0  = W2[(k+0)*HH + j];
        float w1  = W2[(k+1)*HH + j];
        float w2v = W2[(k+2)*HH + j];
        float w3  = W2[(k+3)*HH + j];
        #pragma unroll
        for (int m = 0; m < 8; m++) {
            float4 hv = *(const float4*)&hrow[m * HH + k];
            acc[m] = fmaf(hv.x, w0, fmaf(hv.y, w1, fmaf(hv.z, w2v, fmaf(hv.w, w3, acc[m]))));
        }
    }
    const float bj = b2[j];
    #pragma unroll
    for (int m = 0; m < 8; m++)
        seq[base + (size_t)(mh * 8 + m) * HH + j] = fmaxf(acc[m] * (1.f/9.f) + bj, 0.f);
}

// ---------------------------------------------------------------------------
// Kernel 3: transpose W_ih [384,128] -> WT [128,384]
// ---------------------------------------------------------------------------
__global__ void transpose_wih(const float* __restrict__ W, float* __restrict__ WT)
{
    int idx = blockIdx.x * 256 + threadIdx.x;
    if (idx < 3 * RHH * RHH) {
        int jj = idx / RHH, kk = idx - jj * RHH;
        WT[kk * (3 * RHH) + jj] = W[idx];
    }
}

// ---------------------------------------------------------------------------
// Kernel 4: xg = seq @ W_ih^T + b_ih   [8192,128]@[128,384]
// ---------------------------------------------------------------------------
__global__ __launch_bounds__(384) void xg_kernel(
    const float* __restrict__ seq, const float* __restrict__ WT,
    const float* __restrict__ b_ih, float* __restrict__ xg)
{
    const int tid = threadIdx.x;
    const int m0 = blockIdx.x * 8;
    const float* srow = seq + (size_t)m0 * RHH;
    float acc[8];
    const float bv = b_ih[tid];
    #pragma unroll
    for (int mi = 0; mi < 8; mi++) acc[mi] = bv;
    for (int k = 0; k < RHH; k += 4) {
        float w0 = WT[(k+0)*384 + tid];
        float w1 = WT[(k+1)*384 + tid];
        float w2 = WT[(k+2)*384 + tid];
        float w3 = WT[(k+3)*384 + tid];
        #pragma unroll
        for (int mi = 0; mi < 8; mi++) {
            float4 sv = *(const float4*)(srow + mi * RHH + k);
            acc[mi] = fmaf(sv.x, w0, fmaf(sv.y, w1, fmaf(sv.z, w2, fmaf(sv.w, w3, acc[mi]))));
        }
    }
    #pragma unroll
    for (int mi = 0; mi < 8; mi++)
        xg[(size_t)(m0 + mi) * 384 + tid] = acc[mi];
}

// ---------------------------------------------------------------------------
// Kernel 5: GRU -- R11: 1024 threads (16 waves) per batch element.
//
// Why: R8/R9 (512 thr) require 49152/512 = 96 weight floats/thread; the
// compiler allocated only 88 VGPRs -> weights were NOT register-resident
// (remat/AGPR-shuffle), and measured VALU-busy on active CUs (~77%) is ~2x
// the algorithm's hand-counted VALU -- phantom instructions per step.
// At 1024 threads the footprint is 49152/1024 = 48 floats/thread:
//   thread (i,kq): i = tid>>3 owns ONE unit x 3 gates over the 16-float
//   k-slice [16kq,16kq+16).  wr/wz/wn[4] float4 = 48 VGPRs, fits at
//   4 waves/EU (cap 128) -> plain VGPRs, no remat.
// Same 3-stage 8-lane DPP butterfly as R9 (xor1+xor2+mir7).  fma total per
// SIMD unchanged (work invariant).  DS/step: 64 h-reads (b128, 2-way max
// bank aliasing via p=(m+kq)&3 rotation = free) + 16 xg (b128, broadcast,
// all 32 banks) + 16 masked b32 writes (consecutive words).  16 waves/CU
// also doubles latency hiding for the chunk refill.  84 KB LDS -> 1 blk/CU.
// ---------------------------------------------------------------------------
#define CHUNK 32
#define XGB_FLOATS (CHUNK * HH * 4)      // 16384 floats = 64 KB

__global__ __launch_bounds__(1024)
__attribute__((amdgpu_waves_per_eu(4, 4)))
void gru_kernel(
    const float* __restrict__ xg, const float* __restrict__ W_hh,
    const float* __restrict__ b_hh, const float* __restrict__ Wp,
    const float* __restrict__ bp, float* __restrict__ out)
{
    __shared__ float xgbuf[XGB_FLOATS];          // [tl][i][{xr,xz,xn,pad}]
    __shared__ float houtb[(CHUNK + 2) * HH];    // rows 1..32 = h(t); row 32 also carry
    __shared__ float wps[2 * RHH + 2];           // Wp + bp

    const int b   = blockIdx.x;
    const int tid = threadIdx.x;
    const int kq  = tid & 7;       // k-eighth, lane bits 0-2 (DPP butterfly domain)
    const int i   = tid >> 3;      // hidden unit 0..127

    // ---- preload W_hh slices: rows {i, 128+i, 256+i}, cols [16kq,16kq+16),
    // phase-rotated p=(m+kq)&3 (matches the h-read rotation below).
    float4 wr[4], wz[4], wn[4];
    int hof[4];
    {
        const float* w0 = W_hh + (size_t)i * RHH + kq * 16;
        #pragma unroll
        for (int m = 0; m < 4; m++) {
            const int off = 4 * ((m + kq) & 3);
            hof[m] = kq * 16 + off;
            wr[m] = *(const float4*)(w0 + off);
            wz[m] = *(const float4*)(w0 + RHH * RHH + off);
            wn[m] = *(const float4*)(w0 + 2 * RHH * RHH + off);
        }
    }
    const float bhr = b_hh[i];
    const float bhz = b_hh[RHH + i];
    const float bhn = b_hh[2 * RHH + i];

    if (tid < 2 * RHH) wps[tid] = Wp[tid];
    if (tid < 2)       wps[2 * RHH + tid] = bp[tid];
    if (tid < HH)      houtb[CHUNK * HH + tid] = 0.f;   // carry row = h(-1) = 0
    float hprev = 0.f;

    const float* xbase = xg + (size_t)b * TTT * 3 * RHH;
    float* outb = out + (size_t)b * TTT * 2;

    for (int c = 0; c < TTT / CHUNK; c++) {
        // ---- refill xgbuf for chunk c, repacking to [tl][i][{r,z,n,pad}]
        #pragma unroll
        for (int k2 = 0; k2 < 4; k2++) {
            int slot = tid + (k2 << 10);         // 0..4095
            int tl = slot >> 7, ii = slot & 127;
            const float* gsrc = xbase + (size_t)(c * CHUNK + tl) * 384 + ii;
            float4 v;
            v.x = gsrc[0]; v.y = gsrc[128]; v.z = gsrc[256]; v.w = 0.f;
            *(float4*)&xgbuf[slot << 2] = v;
        }
        // ---- project previous chunk: out = houtb[1..32] @ Wp + bp (512 thr)
        if (c > 0 && tid < 512) {
            const int s  = tid & 7;              // 16-float k-slice
            const int cc = (tid >> 3) & 1;
            const int tl = tid >> 4;             // 0..31
            const float* hr = &houtb[(tl + 1) * HH + s * 16];
            float acc = 0.f;
            #pragma unroll
            for (int m = 0; m < 16; m += 4) {
                float4 hv = *(const float4*)(hr + m);
                int k = s * 16 + m;
                acc = fmaf(hv.x, wps[(k+0)*2 + cc],
                      fmaf(hv.y, wps[(k+1)*2 + cc],
                      fmaf(hv.z, wps[(k+2)*2 + cc],
                      fmaf(hv.w, wps[(k+3)*2 + cc], acc))));
            }
            acc = dpp_add<DPP_XOR1>(acc);
            acc = dpp_add<DPP_XOR2>(acc);
            acc = dpp_add<DPP_SHL4>(acc);        // valid in lanes s<4
            if (s == 0)
                outb[((c - 1) * CHUNK + tl) * 2 + cc] = acc + wps[2 * RHH + cc];
        }
        __syncthreads();

        // ---- 32 steps; per thread: 4 ds_read_b128 (h) + 1 (xg, pipelined)
        float4 xgv = *(const float4*)&xgbuf[i << 2];   // tl=0 row
        for (int tl = 0; tl < CHUNK; tl++) {
            const float* hrow = &houtb[(tl == 0 ? CHUNK : tl) * HH];
            // prefetch next step's xg row (xgbuf is stable within the chunk)
            float4 xgn = xgv;
            if (tl + 1 < CHUNK)
                xgn = *(const float4*)&xgbuf[((tl + 1) * HH + i) << 2];

            float ar = 0.f, az = 0.f, an = 0.f;
            #pragma unroll
            for (int m = 0; m < 4; m++) {
                float4 hv = *(const float4*)(hrow + hof[m]);
                ar = fmaf(hv.x, wr[m].x, fmaf(hv.y, wr[m].y, fmaf(hv.z, wr[m].z, fmaf(hv.w, wr[m].w, ar))));
                az = fmaf(hv.x, wz[m].x, fmaf(hv.y, wz[m].y, fmaf(hv.z, wz[m].z, fmaf(hv.w, wz[m].w, az))));
                an = fmaf(hv.x, wn[m].x, fmaf(hv.y, wn[m].y, fmaf(hv.z, wn[m].z, fmaf(hv.w, wn[m].w, an))));
            }
            // 8-lane butterfly: xor1, xor2 (quad sums), half-mirror (l^7)
            ar = dpp_add<DPP_XOR1>(ar); ar = dpp_add<DPP_XOR2>(ar); ar = dpp_add<DPP_MIR7>(ar);
            az = dpp_add<DPP_XOR1>(az); az = dpp_add<DPP_XOR2>(az); az = dpp_add<DPP_MIR7>(az);
            an = dpp_add<DPP_XOR1>(an); an = dpp_add<DPP_XOR2>(an); an = dpp_add<DPP_MIR7>(an);

            float sr = xgv.x + ar + bhr;
            float sz = xgv.y + az + bhz;
            float rg = 1.f / (1.f + __expf(-sr));
            float zg = 1.f / (1.f + __expf(-sz));
            float tv = fmaf(rg, an + bhn, xgv.z);
            tv = fminf(fmaxf(tv, -15.f), 15.f);
            float e2 = __expf(-2.f * tv);
            float ng = (1.f - e2) / (1.f + e2);
            hprev = fmaf(zg, hprev, (1.f - zg) * ng);
            if (kq == 0) houtb[(tl + 1) * HH + i] = hprev;
            xgv = xgn;
            __syncthreads();
        }
    }

    // ---- project the last chunk (512 thr)
    if (tid < 512) {
        const int s  = tid & 7;
        const int cc = (tid >> 3) & 1;
        const int tl = tid >> 4;
        const float* hr = &houtb[(tl + 1) * HH + s * 16];
        float acc = 0.f;
        #pragma unroll
        for (int m = 0; m < 16; m += 4) {
            float4 hv = *(const float4*)(hr + m);
            int k = s * 16 + m;
            acc = fmaf(hv.x, wps[(k+0)*2 + cc],
                  fmaf(hv.y, wps[(k+1)*2 + cc],
                  fmaf(hv.z, wps[(k+2)*2 + cc],
                  fmaf(hv.w, wps[(k+3)*2 + cc], acc))));
        }
        acc = dpp_add<DPP_XOR1>(acc);
        acc = dpp_add<DPP_XOR2>(acc);
        acc = dpp_add<DPP_SHL4>(acc);
        if (s == 0)
            outb[((TTT / CHUNK - 1) * CHUNK + tl) * 2 + cc] = acc + wps[2 * RHH + cc];
    }
}

extern "C" void kernel_launch(void* const* d_in, const int* in_sizes, int n_in,
                              void* d_out, int out_size, void* d_ws, size_t ws_size,
                              hipStream_t stream)
{
    const float* x      = (const float*)d_in[0];
    const int*   eidx   = (const int*)d_in[1];
    const int*   runner = (const int*)d_in[2];
    const float* W1     = (const float*)d_in[3];
    const float* b1     = (const float*)d_in[4];
    const float* W2     = (const float*)d_in[5];
    const float* b2     = (const float*)d_in[6];
    const float* W_ih   = (const float*)d_in[7];
    const float* W_hh   = (const float*)d_in[8];
    const float* b_ih   = (const float*)d_in[9];
    const float* b_hh   = (const float*)d_in[10];
    const float* Wp     = (const float*)d_in[11];
    const float* bp     = (const float*)d_in[12];
    float* out = (float*)d_out;

    float* seq    = (float*)d_ws;                    // 8192*128   [0, 4 MB)
    float* xg     = seq + (size_t)GG * HH;           // 8192*384   [4, 16.6 MB)
    float* WT     = xg + (size_t)GG * 3 * RHH;       // 128*384
    float* hsum_g = xg;   // alias: dead before xg_kernel writes xg

    transpose_wih<<<192, 256, 0, stream>>>(W_ih, WT);
    gcn_hsum<<<GG, 256, 0, stream>>>(x, eidx, runner, W1, b1, hsum_g);
    seq_kernel<<<GG / 16, 256, 0, stream>>>(hsum_g, W2, b2, seq);
    xg_kernel<<<GG / 8, 384, 0, stream>>>(seq, WT, b_ih, xg);
    gru_kernel<<<BBB, 1024, 0, stream>>>(xg, W_hh, b_hh, Wp, bp, out);
}

// Round 6
// 243.949 us; speedup vs baseline: 1.1868x; 1.0942x over previous
//
#include <hip/hip_runtime.h>
#include <hip/hip_bf16.h>
#include <math.h>

#define GG 8192      // graphs = B*T
#define NODESN 23
#define KK 8
#define DIN 16
#define HH 128
#define RHH 128
#define EPG (NODESN*KK)   // 184 edges per graph
#define TTT 128
#define BBB 64

// ---------------------------------------------------------------------------
// DPP cross-lane add (VALU pipe -- NOT the DS pipe, unlike __shfl_xor).
// ---------------------------------------------------------------------------
template<int CTRL>
static __device__ __forceinline__ float dpp_add(float v) {
    int x = __builtin_amdgcn_update_dpp(0, __float_as_int(v), CTRL, 0xF, 0xF, true);
    return v + __int_as_float(x);
}
#define DPP_XOR1 0xB1   // quad_perm [1,0,3,2]
#define DPP_XOR2 0x4E   // quad_perm [2,3,0,1]
#define DPP_MIR7 0x141  // row_half_mirror: lane l <-> l^7 within 8-lane half-row
#define DPP_SHL4 0x104  // row_shl:4 (lane l <- lane l+4)

// Pin a float4's components into arch VGPRs: the empty asm "redefines" the
// values, making rematerialization (global reload sunk into the loop) or
// AGPR shuttling of the ORIGINAL definition illegal -- the compiler must
// carry these as live VGPRs.  (R8/R9/R11 all showed VGPR_Count far below the
// weight footprint + ~2x phantom VALU issue: weights were not resident.)
#define PIN4(v4) asm volatile("" : "+v"((v4).x), "+v"((v4).y), "+v"((v4).z), "+v"((v4).w))

// ---------------------------------------------------------------------------
// Kernel 1: per-graph GCN up to hsum (R9 version; R10 fusion regressed).
// ---------------------------------------------------------------------------
__global__ __launch_bounds__(256) void gcn_hsum(
    const float* __restrict__ x, const int* __restrict__ esrc,
    const int* __restrict__ runner,
    const float* __restrict__ W1, const float* __restrict__ b1,
    float* __restrict__ hsum_g)
{
    __shared__ float xs[NODESN * DIN];
    __shared__ int   srcs[EPG];
    __shared__ float t1[NODESN * HH];
    __shared__ float red[256];

    const int g   = blockIdx.x;
    const int tid = threadIdx.x;
    const int j   = tid & 127;
    const int nh  = tid >> 7;

    for (int i = tid; i < NODESN * DIN; i += 256) xs[i] = x[g * NODESN * DIN + i];
    for (int i = tid; i < EPG; i += 256)          srcs[i] = esrc[g * EPG + i] - g * NODESN;

    float w[DIN];
    #pragma unroll
    for (int k = 0; k < DIN; k++) w[k] = W1[k * HH + j];
    const float b1j = b1[j];
    __syncthreads();

    const int n0 = nh * 12;
    const int n1 = nh ? NODESN : 12;
    for (int n = n0; n < n1; n++) {
        float acc = 0.f;
        #pragma unroll
        for (int k = 0; k < DIN; k += 4) {
            float4 xv = *(const float4*)&xs[n * DIN + k];
            acc = fmaf(xv.x, w[k], fmaf(xv.y, w[k+1], fmaf(xv.z, w[k+2], fmaf(xv.w, w[k+3], acc))));
        }
        t1[n * HH + j] = acc;
    }
    __syncthreads();

    const int r = runner[g];
    float part = 0.f;
    for (int slot = nh; slot < 9; slot += 2) {
        int node = (slot < 8) ? srcs[r * KK + slot] : r;
        float acc = t1[node * HH + j];
        #pragma unroll
        for (int k = 0; k < KK; k++) acc += t1[srcs[node * KK + k] * HH + j];
        part += fmaxf(acc * (1.f / 9.f) + b1j, 0.f);
    }
    red[tid] = part;
    __syncthreads();
    if (tid < HH) hsum_g[(size_t)g * HH + tid] = red[tid] + red[tid + 128];
}

// ---------------------------------------------------------------------------
// Kernel 2: seq = relu((1/9) * hsum @ W2 + b2), 16 graphs per block (R9).
// ---------------------------------------------------------------------------
__global__ __launch_bounds__(256) void seq_kernel(
    const float* __restrict__ hsum_g, const float* __restrict__ W2,
    const float* __restrict__ b2, float* __restrict__ seq)
{
    __shared__ float hs[16 * HH];
    const int tid = threadIdx.x;
    const int j = tid & 127, mh = tid >> 7;
    const size_t base = (size_t)blockIdx.x * 16 * HH;

    for (int v = tid; v < 16 * HH / 4; v += 256)
        ((float4*)hs)[v] = ((const float4*)(hsum_g + base))[v];
    __syncthreads();

    float acc[8];
    #pragma unroll
    for (int m = 0; m < 8; m++) acc[m] = 0.f;
    const float* hrow = hs + mh * 8 * HH;
    for (int k = 0; k < HH; k += 4) {
        float w0  = W2[(k+0)*HH + j];
        float w1  = W2[(k+1)*HH + j];
        float w2v = W2[(k+2)*HH + j];
        float w3  = W2[(k+3)*HH + j];
        #pragma unroll
        for (int m = 0; m < 8; m++) {
            float4 hv = *(const float4*)&hrow[m * HH + k];
            acc[m] = fmaf(hv.x, w0, fmaf(hv.y, w1, fmaf(hv.z, w2v, fmaf(hv.w, w3, acc[m]))));
        }
    }
    const float bj = b2[j];
    #pragma unroll
    for (int m = 0; m < 8; m++)
        seq[base + (size_t)(mh * 8 + m) * HH + j] = fmaxf(acc[m] * (1.f/9.f) + bj, 0.f);
}

// ---------------------------------------------------------------------------
// Kernel 3: transpose W_ih [384,128] -> WT [128,384]
// ---------------------------------------------------------------------------
__global__ void transpose_wih(const float* __restrict__ W, float* __restrict__ WT)
{
    int idx = blockIdx.x * 256 + threadIdx.x;
    if (idx < 3 * RHH * RHH) {
        int jj = idx / RHH, kk = idx - jj * RHH;
        WT[kk * (3 * RHH) + jj] = W[idx];
    }
}

// ---------------------------------------------------------------------------
// Kernel 4: xg = seq @ W_ih^T + b_ih   [8192,128]@[128,384]
// ---------------------------------------------------------------------------
__global__ __launch_bounds__(384) void xg_kernel(
    const float* __restrict__ seq, const float* __restrict__ WT,
    const float* __restrict__ b_ih, float* __restrict__ xg)
{
    const int tid = threadIdx.x;
    const int m0 = blockIdx.x * 8;
    const float* srow = seq + (size_t)m0 * RHH;
    float acc[8];
    const float bv = b_ih[tid];
    #pragma unroll
    for (int mi = 0; mi < 8; mi++) acc[mi] = bv;
    for (int k = 0; k < RHH; k += 4) {
        float w0 = WT[(k+0)*384 + tid];
        float w1 = WT[(k+1)*384 + tid];
        float w2 = WT[(k+2)*384 + tid];
        float w3 = WT[(k+3)*384 + tid];
        #pragma unroll
        for (int mi = 0; mi < 8; mi++) {
            float4 sv = *(const float4*)(srow + mi * RHH + k);
            acc[mi] = fmaf(sv.x, w0, fmaf(sv.y, w1, fmaf(sv.z, w2, fmaf(sv.w, w3, acc[mi]))));
        }
    }
    #pragma unroll
    for (int mi = 0; mi < 8; mi++)
        xg[(size_t)(m0 + mi) * 384 + tid] = acc[mi];
}

// ---------------------------------------------------------------------------
// Kernel 5: GRU -- R13: R9 structure (512 thr, best measured: 99.4 us) with
// the weight slices PINNED into arch VGPRs via empty inline asm.
//
// Evidence trail: R8 (512t, 96 wf) VGPR=88; R9 (512t, 96 wf) VGPR=88;
// R11 (1024t, 48 wf) VGPR=56 -- in every case VGPR_Count < weight footprint,
// and VALU-busy on active CUs is ~2x the hand-counted instruction stream.
// The weights were never register-resident (remat into the loop or AGPR
// shuttle with v_accvgpr_read per use).  PIN4 makes remat illegal; at
// waves_per_eu(2,2) the VGPR budget is 256, so ~136 live regs fit without
// spilling.
// ---------------------------------------------------------------------------
#define CHUNK 32
#define XGB_FLOATS (CHUNK * HH * 4)      // 16384 floats = 64 KB

__global__ __launch_bounds__(512)
__attribute__((amdgpu_waves_per_eu(2, 2)))
void gru_kernel(
    const float* __restrict__ xg, const float* __restrict__ W_hh,
    const float* __restrict__ b_hh, const float* __restrict__ Wp,
    const float* __restrict__ bp, float* __restrict__ out)
{
    __shared__ float xgbuf[XGB_FLOATS];          // [tl][i][{xr,xz,xn,pad}]
    __shared__ float houtb[(CHUNK + 2) * HH];    // rows 1..32 = h(t); row 32 also carry
    __shared__ float wps[2 * RHH + 2];           // Wp + bp

    const int b   = blockIdx.x;
    const int tid = threadIdx.x;
    const int kq  = tid & 7;       // k-eighth, lane bits 0-2 (DPP butterfly domain)
    const int i0  = tid >> 3;      // unit pair 0..63
    const int uhf = kq >> 2;       // which unit of the pair this lane's gates handle
    const int u   = 2 * i0 + uhf;  // this lane's gate unit

    // ---- preload W_hh slices: rows {2i0, 2i0+1} x {r,z,n}, cols [16kq,16kq+16),
    // phase-rotated p=(m+kq)&3 (matches the h-read rotation below).
    float4 wr0[4], wz0[4], wn0[4], wr1[4], wz1[4], wn1[4];
    int hof[4];
    {
        const float* w0 = W_hh + (size_t)(2 * i0) * RHH + kq * 16;
        #pragma unroll
        for (int m = 0; m < 4; m++) {
            const int off = 4 * ((m + kq) & 3);
            hof[m] = kq * 16 + off;
            wr0[m] = *(const float4*)(w0 + off);
            wz0[m] = *(const float4*)(w0 + RHH * RHH + off);
            wn0[m] = *(const float4*)(w0 + 2 * RHH * RHH + off);
            wr1[m] = *(const float4*)(w0 + RHH + off);
            wz1[m] = *(const float4*)(w0 + RHH * RHH + RHH + off);
            wn1[m] = *(const float4*)(w0 + 2 * RHH * RHH + RHH + off);
        }
    }
    // ---- force register residency (see header comment)
    #pragma unroll
    for (int m = 0; m < 4; m++) {
        PIN4(wr0[m]); PIN4(wz0[m]); PIN4(wn0[m]);
        PIN4(wr1[m]); PIN4(wz1[m]); PIN4(wn1[m]);
    }
    const float bhr = b_hh[u];
    const float bhz = b_hh[RHH + u];
    const float bhn = b_hh[2 * RHH + u];

    if (tid < 2 * RHH) wps[tid] = Wp[tid];
    if (tid < 2)       wps[2 * RHH + tid] = bp[tid];
    if (tid < HH)      houtb[CHUNK * HH + tid] = 0.f;   // carry row = h(-1) = 0
    float hprev = 0.f;

    const float* xbase = xg + (size_t)b * TTT * 3 * RHH;
    float* outb = out + (size_t)b * TTT * 2;

    for (int c = 0; c < TTT / CHUNK; c++) {
        // ---- refill xgbuf for chunk c, repacking to [tl][i][{r,z,n,pad}]
        #pragma unroll
        for (int k2 = 0; k2 < 8; k2++) {
            int slot = tid + (k2 << 9);          // 0..4095
            int tl = slot >> 7, ii = slot & 127;
            const float* gsrc = xbase + (size_t)(c * CHUNK + tl) * 384 + ii;
            float4 v;
            v.x = gsrc[0]; v.y = gsrc[128]; v.z = gsrc[256]; v.w = 0.f;
            *(float4*)&xgbuf[slot << 2] = v;
        }
        // ---- project previous chunk: out = houtb[1..32] @ Wp + bp
        if (c > 0) {
            const int s  = tid & 7;              // 16-float k-slice
            const int cc = (tid >> 3) & 1;
            const int tl = tid >> 4;             // 0..31
            const float* hr = &houtb[(tl + 1) * HH + s * 16];
            float acc = 0.f;
            #pragma unroll
            for (int m = 0; m < 16; m += 4) {
                float4 hv = *(const float4*)(hr + m);
                int k = s * 16 + m;
                acc = fmaf(hv.x, wps[(k+0)*2 + cc],
                      fmaf(hv.y, wps[(k+1)*2 + cc],
                      fmaf(hv.z, wps[(k+2)*2 + cc],
                      fmaf(hv.w, wps[(k+3)*2 + cc], acc))));
            }
            acc = dpp_add<DPP_XOR1>(acc);
            acc = dpp_add<DPP_XOR2>(acc);
            acc = dpp_add<DPP_SHL4>(acc);        // valid in lanes s<4
            if (s == 0)
                outb[((c - 1) * CHUNK + tl) * 2 + cc] = acc + wps[2 * RHH + cc];
        }
        __syncthreads();

        // ---- 32 steps; per step per thread: 4 ds_read_b128 (h) + 1 (xg,
        // pipelined from previous iteration) + 1 masked write
        float4 xgv = *(const float4*)&xgbuf[u << 2];   // tl=0 row
        for (int tl = 0; tl < CHUNK; tl++) {
            const float* hrow = &houtb[(tl == 0 ? CHUNK : tl) * HH];
            // prefetch next step's xg row (xgbuf is stable within the chunk)
            float4 xgn = xgv;
            if (tl + 1 < CHUNK)
                xgn = *(const float4*)&xgbuf[((tl + 1) * HH + u) << 2];

            float ar0 = 0.f, az0 = 0.f, an0 = 0.f;
            float ar1 = 0.f, az1 = 0.f, an1 = 0.f;
            #pragma unroll
            for (int m = 0; m < 4; m++) {
                float4 hv = *(const float4*)(hrow + hof[m]);
                ar0 = fmaf(hv.x, wr0[m].x, fmaf(hv.y, wr0[m].y, fmaf(hv.z, wr0[m].z, fmaf(hv.w, wr0[m].w, ar0))));
                az0 = fmaf(hv.x, wz0[m].x, fmaf(hv.y, wz0[m].y, fmaf(hv.z, wz0[m].z, fmaf(hv.w, wz0[m].w, az0))));
                an0 = fmaf(hv.x, wn0[m].x, fmaf(hv.y, wn0[m].y, fmaf(hv.z, wn0[m].z, fmaf(hv.w, wn0[m].w, an0))));
                ar1 = fmaf(hv.x, wr1[m].x, fmaf(hv.y, wr1[m].y, fmaf(hv.z, wr1[m].z, fmaf(hv.w, wr1[m].w, ar1))));
                az1 = fmaf(hv.x, wz1[m].x, fmaf(hv.y, wz1[m].y, fmaf(hv.z, wz1[m].z, fmaf(hv.w, wz1[m].w, az1))));
                an1 = fmaf(hv.x, wn1[m].x, fmaf(hv.y, wn1[m].y, fmaf(hv.z, wn1[m].z, fmaf(hv.w, wn1[m].w, an1))));
            }
            // 8-lane butterfly: xor1, xor2 (quad sums), half-mirror (l^7)
            ar0 = dpp_add<DPP_XOR1>(ar0); ar0 = dpp_add<DPP_XOR2>(ar0); ar0 = dpp_add<DPP_MIR7>(ar0);
            az0 = dpp_add<DPP_XOR1>(az0); az0 = dpp_add<DPP_XOR2>(az0); az0 = dpp_add<DPP_MIR7>(az0);
            an0 = dpp_add<DPP_XOR1>(an0); an0 = dpp_add<DPP_XOR2>(an0); an0 = dpp_add<DPP_MIR7>(an0);
            ar1 = dpp_add<DPP_XOR1>(ar1); ar1 = dpp_add<DPP_XOR2>(ar1); ar1 = dpp_add<DPP_MIR7>(ar1);
            az1 = dpp_add<DPP_XOR1>(az1); az1 = dpp_add<DPP_XOR2>(az1); az1 = dpp_add<DPP_MIR7>(az1);
            an1 = dpp_add<DPP_XOR1>(an1); an1 = dpp_add<DPP_XOR2>(an1); an1 = dpp_add<DPP_MIR7>(an1);

            // lane-specialized gates: lower half-group -> unit 2i0, upper -> 2i0+1
            float ar = uhf ? ar1 : ar0;
            float az = uhf ? az1 : az0;
            float an = uhf ? an1 : an0;

            float sr = xgv.x + ar + bhr;
            float sz = xgv.y + az + bhz;
            float rg = 1.f / (1.f + __expf(-sr));
            float zg = 1.f / (1.f + __expf(-sz));
            float tv = fmaf(rg, an + bhn, xgv.z);
            tv = fminf(fmaxf(tv, -15.f), 15.f);
            float e2 = __expf(-2.f * tv);
            float ng = (1.f - e2) / (1.f + e2);
            hprev = fmaf(zg, hprev, (1.f - zg) * ng);
            if ((kq & 3) == 0) houtb[(tl + 1) * HH + u] = hprev;  // kq=0 -> 2i0, kq=4 -> 2i0+1
            xgv = xgn;
            __syncthreads();
        }
    }

    // ---- project the last chunk
    {
        const int s  = tid & 7;
        const int cc = (tid >> 3) & 1;
        const int tl = tid >> 4;
        const float* hr = &houtb[(tl + 1) * HH + s * 16];
        float acc = 0.f;
        #pragma unroll
        for (int m = 0; m < 16; m += 4) {
            float4 hv = *(const float4*)(hr + m);
            int k = s * 16 + m;
            acc = fmaf(hv.x, wps[(k+0)*2 + cc],
                  fmaf(hv.y, wps[(k+1)*2 + cc],
                  fmaf(hv.z, wps[(k+2)*2 + cc],
                  fmaf(hv.w, wps[(k+3)*2 + cc], acc))));
        }
        acc = dpp_add<DPP_XOR1>(acc);
        acc = dpp_add<DPP_XOR2>(acc);
        acc = dpp_add<DPP_SHL4>(acc);
        if (s == 0)
            outb[((TTT / CHUNK - 1) * CHUNK + tl) * 2 + cc] = acc + wps[2 * RHH + cc];
    }
}

extern "C" void kernel_launch(void* const* d_in, const int* in_sizes, int n_in,
                              void* d_out, int out_size, void* d_ws, size_t ws_size,
                              hipStream_t stream)
{
    const float* x      = (const float*)d_in[0];
    const int*   eidx   = (const int*)d_in[1];
    const int*   runner = (const int*)d_in[2];
    const float* W1     = (const float*)d_in[3];
    const float* b1     = (const float*)d_in[4];
    const float* W2     = (const float*)d_in[5];
    const float* b2     = (const float*)d_in[6];
    const float* W_ih   = (const float*)d_in[7];
    const float* W_hh   = (const float*)d_in[8];
    const float* b_ih   = (const float*)d_in[9];
    const float* b_hh   = (const float*)d_in[10];
    const float* Wp     = (const float*)d_in[11];
    const float* bp     = (const float*)d_in[12];
    float* out = (float*)d_out;

    float* seq    = (float*)d_ws;                    // 8192*128   [0, 4 MB)
    float* xg     = seq + (size_t)GG * HH;           // 8192*384   [4, 16.6 MB)
    float* WT     = xg + (size_t)GG * 3 * RHH;       // 128*384
    float* hsum_g = xg;   // alias: dead before xg_kernel writes xg

    transpose_wih<<<192, 256, 0, stream>>>(W_ih, WT);
    gcn_hsum<<<GG, 256, 0, stream>>>(x, eidx, runner, W1, b1, hsum_g);
    seq_kernel<<<GG / 16, 256, 0, stream>>>(hsum_g, W2, b2, seq);
    xg_kernel<<<GG / 8, 384, 0, stream>>>(seq, WT, b_ih, xg);
    gru_kernel<<<BBB, 512, 0, stream>>>(xg, W_hh, b_hh, Wp, bp, out);
}

// Round 7
// 242.934 us; speedup vs baseline: 1.1917x; 1.0042x over previous
//
#include <hip/hip_runtime.h>
#include <hip/hip_bf16.h>
#include <math.h>

#define GG 8192      // graphs = B*T
#define NODESN 23
#define KK 8
#define DIN 16
#define HH 128
#define RHH 128
#define EPG (NODESN*KK)   // 184 edges per graph
#define TTT 128
#define BBB 64

// ---------------------------------------------------------------------------
// DPP cross-lane add (VALU pipe -- NOT the DS pipe, unlike __shfl_xor).
// ---------------------------------------------------------------------------
template<int CTRL>
static __device__ __forceinline__ float dpp_add(float v) {
    int x = __builtin_amdgcn_update_dpp(0, __float_as_int(v), CTRL, 0xF, 0xF, true);
    return v + __int_as_float(x);
}
#define DPP_XOR1 0xB1   // quad_perm [1,0,3,2]
#define DPP_XOR2 0x4E   // quad_perm [2,3,0,1]
#define DPP_MIR7 0x141  // row_half_mirror: lane l <-> l^7 within 8-lane half-row
#define DPP_SHL4 0x104  // row_shl:4 (lane l <- lane l+4)

#define PIN4(v4) asm volatile("" : "+v"((v4).x), "+v"((v4).y), "+v"((v4).z), "+v"((v4).w))

// ---------------------------------------------------------------------------
// Kernel 1 (R14): per-graph GCN layer-1 + aggregation + FUSED layer-2 row.
// 1 graph/block, 256 threads, 8192 blocks -> 32 blocks/CU in flight (the
// occupancy R10's 4-graph fusion lost; that was the regression cause).
//
// DS-pipe cut via SCALARIZATION: all x-row reads and all edge-index reads
// have wave-uniform addresses.  nhu = readfirstlane(tid>>7) makes the
// uniformity PROVABLE to the compiler, so these lower to s_load (SMEM pipe,
// no DS/VMEM/VALU issue) instead of the previous ~93 broadcast LDS reads
// per thread (48 xs b128 + 45 srcs b32).  xs/srcs staging deleted.
// Remaining DS/thread: 12 t1 writes + 45 t1 gathers + red/hs ~25.
//
// Layer-2 fusion: hs row (128) is in LDS; seq = relu((hs@W2)/9 + b2) is one
// 128-dot per column -- halves split k (64 each), combined via red.  W2
// halves (32 KB) stay L1-resident across the block's waves and the 32
// co-resident blocks.  hsum never touches HBM; seq_kernel deleted.
// ---------------------------------------------------------------------------
__global__ __launch_bounds__(256) void gcn_seq(
    const float* __restrict__ x, const int* __restrict__ esrc,
    const int* __restrict__ runner,
    const float* __restrict__ W1, const float* __restrict__ b1,
    const float* __restrict__ W2, const float* __restrict__ b2,
    float* __restrict__ seq)
{
    __shared__ float t1[NODESN * HH];   // 11776 B
    __shared__ float red[256];          //  1024 B
    __shared__ float hs[HH];            //   512 B

    const int g   = blockIdx.x;
    const int tid = threadIdx.x;
    const int j   = tid & 127;
    // wave-uniform half index, provably uniform via readfirstlane ->
    // downstream uniform-address loads scalarize to s_load.
    const int nhu = __builtin_amdgcn_readfirstlane(tid >> 7);

    // ---- W1 column j -> registers
    float w[DIN];
    #pragma unroll
    for (int k = 0; k < DIN; k++) w[k] = W1[k * HH + j];
    const float b1j = b1[j];

    // ---- phase 1: t1 = x @ W1 (pre-bias); x rows read scalar (uniform addr)
    const float* xgp = x + (size_t)g * NODESN * DIN;
    const int n0 = nhu ? 12 : 0;
    const int n1 = nhu ? NODESN : 12;
    for (int n = n0; n < n1; n++) {
        const float4* xr = (const float4*)(xgp + n * DIN);
        float4 a0 = xr[0], a1 = xr[1], a2 = xr[2], a3 = xr[3];
        float acc;
        acc = fmaf(a0.x, w[0],  fmaf(a0.y, w[1],  fmaf(a0.z, w[2],  fmaf(a0.w, w[3],
              fmaf(a1.x, w[4],  fmaf(a1.y, w[5],  fmaf(a1.z, w[6],  fmaf(a1.w, w[7],
              fmaf(a2.x, w[8],  fmaf(a2.y, w[9],  fmaf(a2.z, w[10], fmaf(a2.w, w[11],
              fmaf(a3.x, w[12], fmaf(a3.y, w[13], fmaf(a3.z, w[14], fmaf(a3.w, w[15],
              0.f))))))))))))))));
        t1[n * HH + j] = acc;
    }
    __syncthreads();

    // ---- phase 2: runner-neighborhood aggregation; edge indices read
    // scalar (uniform chain: r -> node -> sources), t1 gathers stay DS.
    const int* eg = esrc + (size_t)g * EPG;
    const int gb = g * NODESN;
    const int r  = runner[g];
    float part = 0.f;
    for (int slot = nhu; slot < 9; slot += 2) {
        int node = (slot < 8) ? (eg[r * KK + slot] - gb) : r;
        float acc = t1[node * HH + j];
        #pragma unroll
        for (int k = 0; k < KK; k++) acc += t1[(eg[node * KK + k] - gb) * HH + j];
        part += fmaxf(acc * (1.f / 9.f) + b1j, 0.f);
    }
    red[tid] = part;
    __syncthreads();
    if (tid < HH) hs[tid] = red[tid] + red[tid + 128];
    __syncthreads();   // hs ready; also: all red reads done -> red reusable

    // ---- phase 3 (fused layer-2): seq = relu((hs @ W2) / 9 + b2)
    {
        const int k0 = nhu * 64;
        float acc = 0.f;
        #pragma unroll 4
        for (int kk = 0; kk < 64; kk += 4) {
            int k = k0 + kk;
            float4 hv = *(const float4*)&hs[k];
            acc = fmaf(hv.x, W2[(k + 0) * HH + j],
                  fmaf(hv.y, W2[(k + 1) * HH + j],
                  fmaf(hv.z, W2[(k + 2) * HH + j],
                  fmaf(hv.w, W2[(k + 3) * HH + j], acc))));
        }
        red[tid] = acc;
        __syncthreads();
        if (tid < HH)
            seq[(size_t)g * HH + tid] =
                fmaxf((red[tid] + red[tid + 128]) * (1.f / 9.f) + b2[tid], 0.f);
    }
}

// ---------------------------------------------------------------------------
// Kernel 3: transpose W_ih [384,128] -> WT [128,384]
// ---------------------------------------------------------------------------
__global__ void transpose_wih(const float* __restrict__ W, float* __restrict__ WT)
{
    int idx = blockIdx.x * 256 + threadIdx.x;
    if (idx < 3 * RHH * RHH) {
        int jj = idx / RHH, kk = idx - jj * RHH;
        WT[kk * (3 * RHH) + jj] = W[idx];
    }
}

// ---------------------------------------------------------------------------
// Kernel 4: xg = seq @ W_ih^T + b_ih   [8192,128]@[128,384]
// ---------------------------------------------------------------------------
__global__ __launch_bounds__(384) void xg_kernel(
    const float* __restrict__ seq, const float* __restrict__ WT,
    const float* __restrict__ b_ih, float* __restrict__ xg)
{
    const int tid = threadIdx.x;
    const int m0 = blockIdx.x * 8;
    const float* srow = seq + (size_t)m0 * RHH;
    float acc[8];
    const float bv = b_ih[tid];
    #pragma unroll
    for (int mi = 0; mi < 8; mi++) acc[mi] = bv;
    for (int k = 0; k < RHH; k += 4) {
        float w0 = WT[(k+0)*384 + tid];
        float w1 = WT[(k+1)*384 + tid];
        float w2 = WT[(k+2)*384 + tid];
        float w3 = WT[(k+3)*384 + tid];
        #pragma unroll
        for (int mi = 0; mi < 8; mi++) {
            float4 sv = *(const float4*)(srow + mi * RHH + k);
            acc[mi] = fmaf(sv.x, w0, fmaf(sv.y, w1, fmaf(sv.z, w2, fmaf(sv.w, w3, acc[mi]))));
        }
    }
    #pragma unroll
    for (int mi = 0; mi < 8; mi++)
        xg[(size_t)(m0 + mi) * 384 + tid] = acc[mi];
}

// ---------------------------------------------------------------------------
// Kernel 5: GRU (byte-identical to R13: 512 thr, 98.5 us -- control).
// ---------------------------------------------------------------------------
#define CHUNK 32
#define XGB_FLOATS (CHUNK * HH * 4)      // 16384 floats = 64 KB

__global__ __launch_bounds__(512)
__attribute__((amdgpu_waves_per_eu(2, 2)))
void gru_kernel(
    const float* __restrict__ xg, const float* __restrict__ W_hh,
    const float* __restrict__ b_hh, const float* __restrict__ Wp,
    const float* __restrict__ bp, float* __restrict__ out)
{
    __shared__ float xgbuf[XGB_FLOATS];          // [tl][i][{xr,xz,xn,pad}]
    __shared__ float houtb[(CHUNK + 2) * HH];    // rows 1..32 = h(t); row 32 also carry
    __shared__ float wps[2 * RHH + 2];           // Wp + bp

    const int b   = blockIdx.x;
    const int tid = threadIdx.x;
    const int kq  = tid & 7;       // k-eighth, lane bits 0-2 (DPP butterfly domain)
    const int i0  = tid >> 3;      // unit pair 0..63
    const int uhf = kq >> 2;       // which unit of the pair this lane's gates handle
    const int u   = 2 * i0 + uhf;  // this lane's gate unit

    float4 wr0[4], wz0[4], wn0[4], wr1[4], wz1[4], wn1[4];
    int hof[4];
    {
        const float* w0 = W_hh + (size_t)(2 * i0) * RHH + kq * 16;
        #pragma unroll
        for (int m = 0; m < 4; m++) {
            const int off = 4 * ((m + kq) & 3);
            hof[m] = kq * 16 + off;
            wr0[m] = *(const float4*)(w0 + off);
            wz0[m] = *(const float4*)(w0 + RHH * RHH + off);
            wn0[m] = *(const float4*)(w0 + 2 * RHH * RHH + off);
            wr1[m] = *(const float4*)(w0 + RHH + off);
            wz1[m] = *(const float4*)(w0 + RHH * RHH + RHH + off);
            wn1[m] = *(const float4*)(w0 + 2 * RHH * RHH + RHH + off);
        }
    }
    #pragma unroll
    for (int m = 0; m < 4; m++) {
        PIN4(wr0[m]); PIN4(wz0[m]); PIN4(wn0[m]);
        PIN4(wr1[m]); PIN4(wz1[m]); PIN4(wn1[m]);
    }
    const float bhr = b_hh[u];
    const float bhz = b_hh[RHH + u];
    const float bhn = b_hh[2 * RHH + u];

    if (tid < 2 * RHH) wps[tid] = Wp[tid];
    if (tid < 2)       wps[2 * RHH + tid] = bp[tid];
    if (tid < HH)      houtb[CHUNK * HH + tid] = 0.f;   // carry row = h(-1) = 0
    float hprev = 0.f;

    const float* xbase = xg + (size_t)b * TTT * 3 * RHH;
    float* outb = out + (size_t)b * TTT * 2;

    for (int c = 0; c < TTT / CHUNK; c++) {
        #pragma unroll
        for (int k2 = 0; k2 < 8; k2++) {
            int slot = tid + (k2 << 9);          // 0..4095
            int tl = slot >> 7, ii = slot & 127;
            const float* gsrc = xbase + (size_t)(c * CHUNK + tl) * 384 + ii;
            float4 v;
            v.x = gsrc[0]; v.y = gsrc[128]; v.z = gsrc[256]; v.w = 0.f;
            *(float4*)&xgbuf[slot << 2] = v;
        }
        if (c > 0) {
            const int s  = tid & 7;              // 16-float k-slice
            const int cc = (tid >> 3) & 1;
            const int tl = tid >> 4;             // 0..31
            const float* hr = &houtb[(tl + 1) * HH + s * 16];
            float acc = 0.f;
            #pragma unroll
            for (int m = 0; m < 16; m += 4) {
                float4 hv = *(const float4*)(hr + m);
                int k = s * 16 + m;
                acc = fmaf(hv.x, wps[(k+0)*2 + cc],
                      fmaf(hv.y, wps[(k+1)*2 + cc],
                      fmaf(hv.z, wps[(k+2)*2 + cc],
                      fmaf(hv.w, wps[(k+3)*2 + cc], acc))));
            }
            acc = dpp_add<DPP_XOR1>(acc);
            acc = dpp_add<DPP_XOR2>(acc);
            acc = dpp_add<DPP_SHL4>(acc);        // valid in lanes s<4
            if (s == 0)
                outb[((c - 1) * CHUNK + tl) * 2 + cc] = acc + wps[2 * RHH + cc];
        }
        __syncthreads();

        float4 xgv = *(const float4*)&xgbuf[u << 2];   // tl=0 row
        for (int tl = 0; tl < CHUNK; tl++) {
            const float* hrow = &houtb[(tl == 0 ? CHUNK : tl) * HH];
            float4 xgn = xgv;
            if (tl + 1 < CHUNK)
                xgn = *(const float4*)&xgbuf[((tl + 1) * HH + u) << 2];

            float ar0 = 0.f, az0 = 0.f, an0 = 0.f;
            float ar1 = 0.f, az1 = 0.f, an1 = 0.f;
            #pragma unroll
            for (int m = 0; m < 4; m++) {
                float4 hv = *(const float4*)(hrow + hof[m]);
                ar0 = fmaf(hv.x, wr0[m].x, fmaf(hv.y, wr0[m].y, fmaf(hv.z, wr0[m].z, fmaf(hv.w, wr0[m].w, ar0))));
                az0 = fmaf(hv.x, wz0[m].x, fmaf(hv.y, wz0[m].y, fmaf(hv.z, wz0[m].z, fmaf(hv.w, wz0[m].w, az0))));
                an0 = fmaf(hv.x, wn0[m].x, fmaf(hv.y, wn0[m].y, fmaf(hv.z, wn0[m].z, fmaf(hv.w, wn0[m].w, an0))));
                ar1 = fmaf(hv.x, wr1[m].x, fmaf(hv.y, wr1[m].y, fmaf(hv.z, wr1[m].z, fmaf(hv.w, wr1[m].w, ar1))));
                az1 = fmaf(hv.x, wz1[m].x, fmaf(hv.y, wz1[m].y, fmaf(hv.z, wz1[m].z, fmaf(hv.w, wz1[m].w, az1))));
                an1 = fmaf(hv.x, wn1[m].x, fmaf(hv.y, wn1[m].y, fmaf(hv.z, wn1[m].z, fmaf(hv.w, wn1[m].w, an1))));
            }
            ar0 = dpp_add<DPP_XOR1>(ar0); ar0 = dpp_add<DPP_XOR2>(ar0); ar0 = dpp_add<DPP_MIR7>(ar0);
            az0 = dpp_add<DPP_XOR1>(az0); az0 = dpp_add<DPP_XOR2>(az0); az0 = dpp_add<DPP_MIR7>(az0);
            an0 = dpp_add<DPP_XOR1>(an0); an0 = dpp_add<DPP_XOR2>(an0); an0 = dpp_add<DPP_MIR7>(an0);
            ar1 = dpp_add<DPP_XOR1>(ar1); ar1 = dpp_add<DPP_XOR2>(ar1); ar1 = dpp_add<DPP_MIR7>(ar1);
            az1 = dpp_add<DPP_XOR1>(az1); az1 = dpp_add<DPP_XOR2>(az1); az1 = dpp_add<DPP_MIR7>(az1);
            an1 = dpp_add<DPP_XOR1>(an1); an1 = dpp_add<DPP_XOR2>(an1); an1 = dpp_add<DPP_MIR7>(an1);

            float ar = uhf ? ar1 : ar0;
            float az = uhf ? az1 : az0;
            float an = uhf ? an1 : an0;

            float sr = xgv.x + ar + bhr;
            float sz = xgv.y + az + bhz;
            float rg = 1.f / (1.f + __expf(-sr));
            float zg = 1.f / (1.f + __expf(-sz));
            float tv = fmaf(rg, an + bhn, xgv.z);
            tv = fminf(fmaxf(tv, -15.f), 15.f);
            float e2 = __expf(-2.f * tv);
            float ng = (1.f - e2) / (1.f + e2);
            hprev = fmaf(zg, hprev, (1.f - zg) * ng);
            if ((kq & 3) == 0) houtb[(tl + 1) * HH + u] = hprev;  // kq=0 -> 2i0, kq=4 -> 2i0+1
            xgv = xgn;
            __syncthreads();
        }
    }

    {
        const int s  = tid & 7;
        const int cc = (tid >> 3) & 1;
        const int tl = tid >> 4;
        const float* hr = &houtb[(tl + 1) * HH + s * 16];
        float acc = 0.f;
        #pragma unroll
        for (int m = 0; m < 16; m += 4) {
            float4 hv = *(const float4*)(hr + m);
            int k = s * 16 + m;
            acc = fmaf(hv.x, wps[(k+0)*2 + cc],
                  fmaf(hv.y, wps[(k+1)*2 + cc],
                  fmaf(hv.z, wps[(k+2)*2 + cc],
                  fmaf(hv.w, wps[(k+3)*2 + cc], acc))));
        }
        acc = dpp_add<DPP_XOR1>(acc);
        acc = dpp_add<DPP_XOR2>(acc);
        acc = dpp_add<DPP_SHL4>(acc);
        if (s == 0)
            outb[((TTT / CHUNK - 1) * CHUNK + tl) * 2 + cc] = acc + wps[2 * RHH + cc];
    }
}

extern "C" void kernel_launch(void* const* d_in, const int* in_sizes, int n_in,
                              void* d_out, int out_size, void* d_ws, size_t ws_size,
                              hipStream_t stream)
{
    const float* x      = (const float*)d_in[0];
    const int*   eidx   = (const int*)d_in[1];
    const int*   runner = (const int*)d_in[2];
    const float* W1     = (const float*)d_in[3];
    const float* b1     = (const float*)d_in[4];
    const float* W2     = (const float*)d_in[5];
    const float* b2     = (const float*)d_in[6];
    const float* W_ih   = (const float*)d_in[7];
    const float* W_hh   = (const float*)d_in[8];
    const float* b_ih   = (const float*)d_in[9];
    const float* b_hh   = (const float*)d_in[10];
    const float* Wp     = (const float*)d_in[11];
    const float* bp     = (const float*)d_in[12];
    float* out = (float*)d_out;

    float* seq = (float*)d_ws;                       // 8192*128   [0, 4 MB)
    float* xg  = seq + (size_t)GG * HH;              // 8192*384   [4, 16.6 MB)
    float* WT  = xg + (size_t)GG * 3 * RHH;          // 128*384

    transpose_wih<<<192, 256, 0, stream>>>(W_ih, WT);
    gcn_seq<<<GG, 256, 0, stream>>>(x, eidx, runner, W1, b1, W2, b2, seq);
    xg_kernel<<<GG / 8, 384, 0, stream>>>(seq, WT, b_ih, xg);
    gru_kernel<<<BBB, 512, 0, stream>>>(xg, W_hh, b_hh, Wp, bp, out);
}